// Round 12
// baseline (180.766 us; speedup 1.0000x reference)
//
#include <hip/hip_runtime.h>
#include <math.h>

// GCN, R12: R11 structure, fp32 rows (stride 32 floats = 128B, float4
// gathers by 8 lanes/node). R6-vs-R7 A/B showed gather BYTES don't matter
// at this structure (latency/inst-bound), so fp16 cvts were pure overhead.
// LDS hand-off rows stride 40 floats (16B-aligned, 2-way banks = free).
// eb packed (src<<8)|(dst&255); padded CSR (int4 blocks, pads -> zero row n).

#define TPB 256
#define BSH 8                 // 256 nodes per bucket
#define BNODES 256
#define MAXBUCK 512
#define CH 4096               // edges per partition block (313 blocks)
#define CAPSH 13              // slab capacity 8192 entries/bucket
#define CAP (1 << CAPSH)

// partition edges into per-bucket slabs; bcursor RELATIVE (memset 0).
// block 0 also zeroes the dummy row n of u1f/u2f.
__global__ void k_part(const int* __restrict__ src, const int* __restrict__ dst,
                       int* __restrict__ bcursor, int* __restrict__ eb,
                       float* __restrict__ u1f, float* __restrict__ u2f,
                       int E, int n, int nbuck) {
    __shared__ int lh[MAXBUCK];
    __shared__ int lbase[MAXBUCK];
    int t = threadIdx.x;
    if (blockIdx.x == 0 && t < 32) {
        u1f[(size_t)n * 32 + t] = 0.f;
        u2f[(size_t)n * 32 + t] = 0.f;
    }
    int chunk0 = blockIdx.x * CH;
    int end = min(chunk0 + CH, E);
    const int4* dst4 = (const int4*)dst;
    const int4* src4 = (const int4*)src;
    for (int i = t; i < nbuck; i += TPB) lh[i] = 0;
    __syncthreads();
    for (int e4 = chunk0 / 4 + t; e4 * 4 < end; e4 += TPB) {
        int base = e4 * 4;
        int4 d = dst4[e4];
        if (base + 0 < end) atomicAdd(&lh[d.x >> BSH], 1);
        if (base + 1 < end) atomicAdd(&lh[d.y >> BSH], 1);
        if (base + 2 < end) atomicAdd(&lh[d.z >> BSH], 1);
        if (base + 3 < end) atomicAdd(&lh[d.w >> BSH], 1);
    }
    __syncthreads();
    for (int i = t; i < nbuck; i += TPB) {
        int c = lh[i];
        lbase[i] = c ? atomicAdd(&bcursor[i], c) : 0;
        lh[i] = 0;
    }
    __syncthreads();
    for (int e4 = chunk0 / 4 + t; e4 * 4 < end; e4 += TPB) {
        int base = e4 * 4;
        int4 d = dst4[e4];
        int4 s = src4[e4];
        #define PUT(c, sv) if (base + c < end) { \
            int b = (d.sv) >> BSH; \
            int r = lbase[b] + atomicAdd(&lh[b], 1); \
            if (r < CAP) \
                eb[((size_t)b << CAPSH) + r] = ((s.sv) << BSH) | ((d.sv) & (BNODES - 1)); }
        PUT(0, x) PUT(1, y) PUT(2, z) PUT(3, w)
        #undef PUT
    }
}

// per bucket: LDS counting sort into PADDED csr segments (4-aligned starts,
// pads = node id n -> zero row). Outputs row_start, cnt4, dinv, u1f rows.
__global__ void k_bucket(const int* __restrict__ eb, const int* __restrict__ bcursor,
                         const float* __restrict__ x,
                         int* __restrict__ csr, int* __restrict__ row_start,
                         int* __restrict__ cnt4, float* __restrict__ dinv,
                         float* __restrict__ u1f, int n) {
    __shared__ int lcnt[BNODES];
    __shared__ int lscan[BNODES];
    __shared__ float ldinv[BNODES];
    int b = blockIdx.x;
    int t = threadIdx.x;
    int node0 = b << BSH;
    int beg = b << CAPSH;
    int end = beg + min(bcursor[b], CAP);
    lcnt[t] = 0;
    __syncthreads();
    for (int i = beg + t; i < end; i += TPB)
        atomicAdd(&lcnt[eb[i] & (BNODES - 1)], 1);
    __syncthreads();
    int v = lcnt[t];
    int pad = (v + 3) & ~3;
    lscan[t] = pad;
    __syncthreads();
    for (int off = 1; off < TPB; off <<= 1) {
        int xx = (t >= off) ? lscan[t - off] : 0;
        __syncthreads();
        lscan[t] += xx;
        __syncthreads();
    }
    int pexcl = lscan[t] - pad;
    int node = node0 + t;
    float dv = rsqrtf(1.0f + (float)v);
    ldinv[t] = dv;
    if (node < n) {
        row_start[node] = beg + pexcl;
        cnt4[node] = pad >> 2;
        dinv[node] = dv;
    }
    __syncthreads();
    lcnt[t] = pexcl;
    __syncthreads();
    for (int i = beg + t; i < end; i += TPB) {
        int e = eb[i];
        int p = atomicAdd(&lcnt[e & (BNODES - 1)], 1);
        csr[beg + p] = e >> BSH;
    }
    __syncthreads();
    for (int p = v; p < pad; ++p) csr[beg + pexcl + p] = n;
    // u1f rows (stride 32 floats; features 18..31 zeroed)
    int nn = min(BNODES, n - node0);
    int tot = nn * 32;
    const float* xb = x + (size_t)node0 * 18;
    float* ub = u1f + (size_t)node0 * 32;
    for (int i = t; i < tot; i += TPB) {
        int nl = i >> 5, f = i & 31;
        ub[i] = (f < 18) ? xb[nl * 18 + f] * ldinv[nl] : 0.f;
    }
}

// fused layer1: agg (8 lanes/node, float4 gathers) -> intra-wave LDS ->
// transform (half-wave per node, W1 col f in 18 VGPRs) -> u2f fp32 rows.
__global__ void k_fused1(const float4* __restrict__ u1q, const int* __restrict__ row_start,
                         const int* __restrict__ cnt4, const int* __restrict__ csr,
                         const float* __restrict__ dinv, const float* __restrict__ W1,
                         const float* __restrict__ b1, float* __restrict__ u2f,
                         int n) {
    __shared__ float lagg[4][8][40];   // stride 40: 16B-aligned, 2-way banks
    int t = threadIdx.x;
    int lane = t & 63, wv = t >> 6;
    int q = lane & 7, grp = lane >> 3;
    int f = lane & 31, h = lane >> 5;
    float w1r[18];
#pragma unroll
    for (int k = 0; k < 18; ++k) w1r[k] = W1[k * 32 + f];
    float b1v = b1[f];
    int node0 = (blockIdx.x * 4 + wv) * 8;
    int node = node0 + grp;
    float4 acc = make_float4(0.f, 0.f, 0.f, 0.f);
    if (node < n) {
        acc = u1q[(size_t)node * 8 + q];          // self term
        int beg = row_start[node];
        int it = cnt4[node];
        const int4* ip = (const int4*)(csr + beg);
        for (int i = 0; i < it; ++i) {
            int4 s = ip[i];
            float4 v0 = u1q[(size_t)s.x * 8 + q];
            float4 v1 = u1q[(size_t)s.y * 8 + q];
            float4 v2 = u1q[(size_t)s.z * 8 + q];
            float4 v3 = u1q[(size_t)s.w * 8 + q];
            acc.x += (v0.x + v1.x) + (v2.x + v3.x);
            acc.y += (v0.y + v1.y) + (v2.y + v3.y);
            acc.z += (v0.z + v1.z) + (v2.z + v3.z);
            acc.w += (v0.w + v1.w) + (v2.w + v3.w);
        }
    }
    *(float4*)&lagg[wv][grp][4 * q] = acc;        // intra-wave hand-off
#pragma unroll
    for (int r = 0; r < 4; ++r) {
        int nl = 2 * r + h;
        int nodeT = node0 + nl;
        if (nodeT < n) {
            const float* rp = lagg[wv][nl];
            float a = 0.f;
#pragma unroll
            for (int k = 0; k < 18; ++k) a = fmaf(rp[k], w1r[k], a);
            float di = dinv[nodeT];
            u2f[(size_t)nodeT * 32 + f] = fmaxf(fmaf(di, a, b1v), 0.f) * di;
        }
    }
}

// fused layer2 + head: agg (8 lanes/node, float4) -> intra-wave LDS ->
// transform (lane = output, W2 col in 32 VGPRs) -> FC(64->2) -> log_softmax.
__global__ void k_fused2(const float4* __restrict__ u2q, const int* __restrict__ row_start,
                         const int* __restrict__ cnt4, const int* __restrict__ csr,
                         const float* __restrict__ dinv, const float* __restrict__ W2,
                         const float* __restrict__ b2, const float* __restrict__ Wfc,
                         const float* __restrict__ bfc, float* __restrict__ out,
                         int n) {
    __shared__ float lagg[4][8][40];
    int t = threadIdx.x;
    int lane = t & 63, wv = t >> 6;
    int q = lane & 7, grp = lane >> 3;
    float w2r[32];
#pragma unroll
    for (int k = 0; k < 32; ++k) w2r[k] = W2[k * 64 + lane];
    float b2v = b2[lane];
    float wf0 = Wfc[lane * 2 + 0], wf1 = Wfc[lane * 2 + 1];
    float bf0 = bfc[0], bf1 = bfc[1];
    int node0 = (blockIdx.x * 4 + wv) * 8;
    int node = node0 + grp;
    float4 acc = make_float4(0.f, 0.f, 0.f, 0.f);
    if (node < n) {
        acc = u2q[(size_t)node * 8 + q];          // self term
        int beg = row_start[node];
        int it = cnt4[node];
        const int4* ip = (const int4*)(csr + beg);
        for (int i = 0; i < it; ++i) {
            int4 s = ip[i];
            float4 v0 = u2q[(size_t)s.x * 8 + q];
            float4 v1 = u2q[(size_t)s.y * 8 + q];
            float4 v2 = u2q[(size_t)s.z * 8 + q];
            float4 v3 = u2q[(size_t)s.w * 8 + q];
            acc.x += (v0.x + v1.x) + (v2.x + v3.x);
            acc.y += (v0.y + v1.y) + (v2.y + v3.y);
            acc.z += (v0.z + v1.z) + (v2.z + v3.z);
            acc.w += (v0.w + v1.w) + (v2.w + v3.w);
        }
    }
    *(float4*)&lagg[wv][grp][4 * q] = acc;
#pragma unroll
    for (int r = 0; r < 8; ++r) {
        int nodeT = node0 + r;
        const float* rp = lagg[wv][r];
        float c0 = 0.f, c1 = 0.f, c2 = 0.f, c3 = 0.f;
#pragma unroll
        for (int k = 0; k < 32; k += 4) {
            c0 = fmaf(rp[k],     w2r[k],     c0);
            c1 = fmaf(rp[k + 1], w2r[k + 1], c1);
            c2 = fmaf(rp[k + 2], w2r[k + 2], c2);
            c3 = fmaf(rp[k + 3], w2r[k + 3], c3);
        }
        float a = (c0 + c1) + (c2 + c3);
        float v = (nodeT < n) ? fmaxf(fmaf(dinv[nodeT], a, b2v), 0.f) : 0.f;
        float l0 = v * wf0;
        float l1 = v * wf1;
#pragma unroll
        for (int off = 32; off >= 1; off >>= 1) {
            l0 += __shfl_xor(l0, off, 64);
            l1 += __shfl_xor(l1, off, 64);
        }
        if (lane == 0 && nodeT < n) {
            l0 += bf0;
            l1 += bf1;
            float m2 = fmaxf(l0, l1);
            float lse = m2 + logf(expf(l0 - m2) + expf(l1 - m2));
            out[nodeT * 2 + 0] = l0 - lse;
            out[nodeT * 2 + 1] = l1 - lse;
        }
    }
}

extern "C" void kernel_launch(void* const* d_in, const int* in_sizes, int n_in,
                              void* d_out, int out_size, void* d_ws, size_t ws_size,
                              hipStream_t stream) {
    const float* x   = (const float*)d_in[0];
    const int*   ei  = (const int*)d_in[1];
    const float* W1  = (const float*)d_in[2];
    const float* b1  = (const float*)d_in[3];
    const float* W2  = (const float*)d_in[4];
    const float* b2  = (const float*)d_in[5];
    const float* Wfc = (const float*)d_in[6];
    const float* bfc = (const float*)d_in[7];
    float* out = (float*)d_out;

    const int n = in_sizes[0] / 18;
    const int E = in_sizes[1] / 2;
    const int* src = ei;
    const int* dst = ei + E;
    const int nbuck = (n + BNODES - 1) >> BSH;

    // ws: bcursor[nbuck] | row_start[n] | cnt4[n] | dinv[n]
    //  | eb[nbuck*CAP] | csr[nbuck*CAP] | u1f[(n+1)*32 f32] | u2f[(n+1)*32 f32]
    char* w = (char*)d_ws;
    int*    bcursor   = (int*)w;     w += (size_t)nbuck * 4;
    int*    row_start = (int*)w;     w += (size_t)n * 4;
    int*    cnt4      = (int*)w;     w += (size_t)n * 4;
    float*  dinv      = (float*)w;   w += (size_t)n * 4;
    int*    eb        = (int*)w;     w += (size_t)nbuck * CAP * 4;
    int*    csr       = (int*)w;     w += (size_t)nbuck * CAP * 4;
    w = (char*)(((size_t)w + 127) & ~(size_t)127);
    float*  u1f       = (float*)w;   w += (size_t)(n + 1) * 32 * 4;
    w = (char*)(((size_t)w + 127) & ~(size_t)127);
    float*  u2f       = (float*)w;   w += (size_t)(n + 1) * 32 * 4;

    // ---- CSR build: slab bucket sort with padded segments ----
    hipMemsetAsync(bcursor, 0, (size_t)nbuck * 4, stream);
    k_part<<<(E + CH - 1) / CH, TPB, 0, stream>>>(src, dst, bcursor, eb, u1f, u2f, E, n, nbuck);
    k_bucket<<<nbuck, TPB, 0, stream>>>(eb, bcursor, x, csr, row_start, cnt4, dinv, u1f, n);

    const int waves = (n + 7) / 8;
    const int blocksF = (waves + 3) / 4;

    k_fused1<<<blocksF, TPB, 0, stream>>>((const float4*)u1f, row_start, cnt4, csr,
                                          dinv, W1, b1, u2f, n);
    k_fused2<<<blocksF, TPB, 0, stream>>>((const float4*)u2f, row_start, cnt4, csr,
                                          dinv, W2, b2, Wfc, bfc, out, n);
}